// Round 1
// baseline (768.940 us; speedup 1.0000x reference)
//
#include <hip/hip_runtime.h>
#include <math.h>

#define BATCH 64
#define CH    768
#define NP    1024   // H*W tokens per batch (plane order == token order, invariant)
#define NI    96
#define NT    8
#define EPSF  1e-5f

// ---------------- Kernel 1: per-token mean / rstd ----------------
// grid: BATCH*4, block: 256 threads. Each block: batch b, 256 tokens.
// 64 token-groups (float4) x 4 c-groups, LDS-combine.
__global__ __launch_bounds__(256) void k_stats(const float* __restrict__ x,
                                               float2* __restrict__ stats) {
    int bid = blockIdx.x;
    int b   = bid >> 2;
    int p0  = (bid & 3) << 8;
    int lt  = threadIdx.x & 63;   // token group (4 tokens)
    int cg  = threadIdx.x >> 6;   // channel group 0..3
    const float* xb = x + (size_t)b * CH * NP + p0 + lt * 4;
    float4 s = make_float4(0.f,0.f,0.f,0.f);
    float4 q = make_float4(0.f,0.f,0.f,0.f);
    for (int c = cg; c < CH; c += 4) {
        float4 v = *(const float4*)(xb + (size_t)c * NP);
        s.x += v.x; s.y += v.y; s.z += v.z; s.w += v.w;
        q.x += v.x*v.x; q.y += v.y*v.y; q.z += v.z*v.z; q.w += v.w*v.w;
    }
    __shared__ float4 ls[256];
    __shared__ float4 lq[256];
    ls[threadIdx.x] = s; lq[threadIdx.x] = q;
    __syncthreads();
    if (cg == 0) {
        for (int k = 1; k < 4; k++) {
            float4 s2 = ls[lt + 64*k], q2 = lq[lt + 64*k];
            s.x += s2.x; s.y += s2.y; s.z += s2.z; s.w += s2.w;
            q.x += q2.x; q.y += q2.y; q.z += q2.z; q.w += q2.w;
        }
        const float inv = 1.0f / (float)CH;
        float2* st = stats + (size_t)b * NP + p0 + lt * 4;
        float mu, var;
        mu = s.x * inv; var = q.x * inv - mu * mu; st[0] = make_float2(mu, rsqrtf(var + EPSF));
        mu = s.y * inv; var = q.y * inv - mu * mu; st[1] = make_float2(mu, rsqrtf(var + EPSF));
        mu = s.z * inv; var = q.z * inv - mu * mu; st[2] = make_float2(mu, rsqrtf(var + EPSF));
        mu = s.w * inv; var = q.w * inv - mu * mu; st[3] = make_float2(mu, rsqrtf(var + EPSF));
    }
}

// ---------------- Kernel 2: LN + MLP -> logits ----------------
// grid: BATCH*8, block 256 threads: 128 tokens x 2 channel-halves.
// Each thread: 96 fp32 accumulators; w1 chunk-staged in LDS (broadcast reads).
__global__ __launch_bounds__(256) void k_mlp(const float* __restrict__ x,
        const float2* __restrict__ stats,
        const float* __restrict__ gamma, const float* __restrict__ beta,
        const float* __restrict__ w1, const float* __restrict__ b1,
        const float* __restrict__ w2, const float* __restrict__ b2,
        float* __restrict__ logits) {
    int bid = blockIdx.x;
    int b   = bid >> 3;
    int p0  = (bid & 7) << 7;
    int tid = threadIdx.x;
    int tok = tid & 127;
    int cg  = tid >> 7;                 // 0 or 1
    __shared__ float w1s[128 * NI];     // staging: 48 KB (also reused for combine via stride-97 view)
    __shared__ float comb[128 * 97];    // padded combine buffer (49.7 KB)  -- separate to keep logic simple

    float2 st = stats[(size_t)b * NP + p0 + tok];
    float mu = st.x, rstd = st.y;
    const float* xb = x + (size_t)b * CH * NP + p0 + tok;
    float acc[NI];
#pragma unroll
    for (int i = 0; i < NI; i++) acc[i] = 0.f;

    for (int cc = 0; cc < CH; cc += 128) {
        __syncthreads();
        const float4* src = (const float4*)(w1 + (size_t)cc * NI);
        float4* dst = (float4*)w1s;
        for (int j = tid; j < 128 * NI / 4; j += 256) dst[j] = src[j];
        __syncthreads();
        int cbase = cg * 64;
        for (int ci = 0; ci < 64; ci++) {
            int c = cc + cbase + ci;
            float v = xb[(size_t)c * NP];
            float xn = (v - mu) * rstd * gamma[c] + beta[c];
            const float4* wr = (const float4*)&w1s[(cbase + ci) * NI];
#pragma unroll
            for (int k = 0; k < NI/4; k++) {
                float4 w = wr[k];
                acc[4*k+0] += xn * w.x;
                acc[4*k+1] += xn * w.y;
                acc[4*k+2] += xn * w.z;
                acc[4*k+3] += xn * w.w;
            }
        }
    }
    __syncthreads();
    if (cg == 1) {
        float* dstc = comb + tok * 97;   // odd stride -> conflict-free
#pragma unroll
        for (int i = 0; i < NI; i++) dstc[i] = acc[i];
    }
    __syncthreads();
    if (cg == 0) {
        const float* oth = comb + tok * 97;
        float lg[NT];
#pragma unroll
        for (int n = 0; n < NT; n++) lg[n] = b2[n];
#pragma unroll
        for (int i = 0; i < NI; i++) {
            float h = acc[i] + oth[i] + b1[i];
            h = 0.5f * h * (1.0f + erff(h * 0.70710678118654752f));
#pragma unroll
            for (int n = 0; n < NT; n++) lg[n] += h * w2[i * NT + n];
        }
        float4* op = (float4*)(logits + ((size_t)b * NP + p0 + tok) * NT);
        op[0] = make_float4(lg[0], lg[1], lg[2], lg[3]);
        op[1] = make_float4(lg[4], lg[5], lg[6], lg[7]);
    }
}

// ---------------- Kernel 3: softmax over tokens, g = rstd*attn (in-place), S2 ----------------
// grid: BATCH, block 256 threads; each thread owns 4 tokens.
__global__ __launch_bounds__(256) void k_softmax(float* __restrict__ gbuf,
        const float2* __restrict__ stats, float* __restrict__ S2) {
    int b = blockIdx.x;
    int tid = threadIdx.x;
    float* gb = gbuf + (size_t)b * NP * NT;
    const float2* stb = stats + (size_t)b * NP;
    float l[4][NT];
    float2 st[4];
#pragma unroll
    for (int k = 0; k < 4; k++) {
        int p = tid + 256 * k;
        float4 a = *(const float4*)(gb + p * NT);
        float4 c = *(const float4*)(gb + p * NT + 4);
        l[k][0]=a.x; l[k][1]=a.y; l[k][2]=a.z; l[k][3]=a.w;
        l[k][4]=c.x; l[k][5]=c.y; l[k][6]=c.z; l[k][7]=c.w;
        st[k] = stb[p];
    }
    __shared__ float red[NT][256];
    float m[NT];
#pragma unroll
    for (int n = 0; n < NT; n++)
        m[n] = fmaxf(fmaxf(l[0][n], l[1][n]), fmaxf(l[2][n], l[3][n]));
#pragma unroll
    for (int n = 0; n < NT; n++) red[n][tid] = m[n];
    __syncthreads();
    for (int s = 128; s > 0; s >>= 1) {
        if (tid < s) {
#pragma unroll
            for (int n = 0; n < NT; n++)
                red[n][tid] = fmaxf(red[n][tid], red[n][tid + s]);
        }
        __syncthreads();
    }
#pragma unroll
    for (int n = 0; n < NT; n++) m[n] = red[n][0];
    __syncthreads();

    float e[4][NT];
    float sum[NT];
#pragma unroll
    for (int n = 0; n < NT; n++) sum[n] = 0.f;
#pragma unroll
    for (int k = 0; k < 4; k++)
#pragma unroll
        for (int n = 0; n < NT; n++) {
            e[k][n] = expf(l[k][n] - m[n]);
            sum[n] += e[k][n];
        }
#pragma unroll
    for (int n = 0; n < NT; n++) red[n][tid] = sum[n];
    __syncthreads();
    for (int s = 128; s > 0; s >>= 1) {
        if (tid < s) {
#pragma unroll
            for (int n = 0; n < NT; n++)
                red[n][tid] += red[n][tid + s];
        }
        __syncthreads();
    }
    float inv[NT];
#pragma unroll
    for (int n = 0; n < NT; n++) inv[n] = 1.0f / red[n][0];
    __syncthreads();

    float s2l[NT];
#pragma unroll
    for (int n = 0; n < NT; n++) s2l[n] = 0.f;
#pragma unroll
    for (int k = 0; k < 4; k++) {
        int p = tid + 256 * k;
        float gg[NT];
#pragma unroll
        for (int n = 0; n < NT; n++) {
            gg[n] = st[k].y * (e[k][n] * inv[n]);   // rstd * attn
            s2l[n] += st[k].x * gg[n];              // mu * g
        }
        float4* op = (float4*)(gb + p * NT);
        op[0] = make_float4(gg[0], gg[1], gg[2], gg[3]);
        op[1] = make_float4(gg[4], gg[5], gg[6], gg[7]);
    }
#pragma unroll
    for (int n = 0; n < NT; n++) red[n][tid] = s2l[n];
    __syncthreads();
    for (int s = 128; s > 0; s >>= 1) {
        if (tid < s) {
#pragma unroll
            for (int n = 0; n < NT; n++)
                red[n][tid] += red[n][tid + s];
        }
        __syncthreads();
    }
    if (tid < NT) S2[b * NT + tid] = red[tid][0];
}

// ---------------- Kernel 4: out[b,c,n] = (gamma_c*(x[b,c,:]·g[:,n] - S2[n]) + beta_c)/1024 ----------------
// grid: BATCH*12 (64 channels per block), 256 threads = 4 waves, 16 channels/wave.
__global__ __launch_bounds__(256) void k_out(const float* __restrict__ x,
        const float* __restrict__ g, const float* __restrict__ S2,
        const float* __restrict__ gamma, const float* __restrict__ beta,
        float* __restrict__ out) {
    int b  = blockIdx.x / 12;
    int c0 = (blockIdx.x % 12) * 64;
    int tid = threadIdx.x;
    __shared__ float gT[NT][NP];   // 32 KB, transposed
    __shared__ float s2s[NT];
    const float4* gb4 = (const float4*)(g + (size_t)b * NP * NT);
#pragma unroll
    for (int k = 0; k < 4; k++) {
        int p = k * 256 + tid;
        float4 a = gb4[p * 2];
        float4 c = gb4[p * 2 + 1];
        gT[0][p] = a.x; gT[1][p] = a.y; gT[2][p] = a.z; gT[3][p] = a.w;
        gT[4][p] = c.x; gT[5][p] = c.y; gT[6][p] = c.z; gT[7][p] = c.w;
    }
    if (tid < NT) s2s[tid] = S2[b * NT + tid];
    __syncthreads();

    int wave = tid >> 6, lane = tid & 63;
    for (int ch = 0; ch < 16; ch++) {
        int c = c0 + wave * 16 + ch;
        const float* xr = x + ((size_t)b * CH + c) * NP;
        float acc[NT];
#pragma unroll
        for (int n = 0; n < NT; n++) acc[n] = 0.f;
        for (int k = 0; k < 16; k++) {
            float v = xr[k * 64 + lane];
#pragma unroll
            for (int n = 0; n < NT; n++) acc[n] += v * gT[n][k * 64 + lane];
        }
#pragma unroll
        for (int n = 0; n < NT; n++) {
            for (int off = 32; off > 0; off >>= 1)
                acc[n] += __shfl_down(acc[n], off, 64);
        }
        if (lane == 0) {
            const float s = 1.0f / (float)NP;
            float ga = gamma[c] * s, be = beta[c] * s;
            float4 o0 = make_float4(ga*(acc[0]-s2s[0])+be, ga*(acc[1]-s2s[1])+be,
                                    ga*(acc[2]-s2s[2])+be, ga*(acc[3]-s2s[3])+be);
            float4 o1 = make_float4(ga*(acc[4]-s2s[4])+be, ga*(acc[5]-s2s[5])+be,
                                    ga*(acc[6]-s2s[6])+be, ga*(acc[7]-s2s[7])+be);
            float4* op = (float4*)(out + ((size_t)b * CH + c) * NT);
            op[0] = o0; op[1] = o1;
        }
    }
}

extern "C" void kernel_launch(void* const* d_in, const int* in_sizes, int n_in,
                              void* d_out, int out_size, void* d_ws, size_t ws_size,
                              hipStream_t stream) {
    const float* x     = (const float*)d_in[0];
    const float* gamma = (const float*)d_in[1];
    const float* beta  = (const float*)d_in[2];
    const float* w1    = (const float*)d_in[3];
    const float* b1    = (const float*)d_in[4];
    const float* w2    = (const float*)d_in[5];
    const float* b2    = (const float*)d_in[6];
    float* out = (float*)d_out;

    char* ws = (char*)d_ws;
    float2* stats = (float2*)ws;                                  // 64*1024*8B   = 512 KB
    float*  gbuf  = (float*)(ws + (size_t)BATCH * NP * sizeof(float2));  // 2 MB (logits -> g in place)
    float*  S2    = (float*)(ws + (size_t)BATCH * NP * sizeof(float2)
                                 + (size_t)BATCH * NP * NT * sizeof(float)); // 2 KB

    k_stats  <<<BATCH * 4,  256, 0, stream>>>(x, stats);
    k_mlp    <<<BATCH * 8,  256, 0, stream>>>(x, stats, gamma, beta, w1, b1, w2, b2, gbuf);
    k_softmax<<<BATCH,      256, 0, stream>>>(gbuf, stats, S2);
    k_out    <<<BATCH * 12, 256, 0, stream>>>(x, gbuf, S2, gamma, beta, out);
}

// Round 2
// 380.979 us; speedup vs baseline: 2.0183x; 2.0183x over previous
//
#include <hip/hip_runtime.h>
#include <math.h>

#define BATCH 64
#define CH    768
#define NP    1024
#define NI    96
#define NT    8
#define EPSF  1e-5f

typedef __attribute__((ext_vector_type(8))) short  short8;
typedef __attribute__((ext_vector_type(4))) float  f32x4;

__device__ __forceinline__ unsigned short f2bf(float f) {
    unsigned int u = __float_as_uint(f);
    u += 0x7FFFu + ((u >> 16) & 1u);          // round-to-nearest-even
    return (unsigned short)(u >> 16);
}

// ---------------- Kernel 0: pack w1 (fp32 [768][96]) -> bf16 B-fragment layout ----------------
// layout: w1f[((ks*6 + nt)*64 + lane)*8 + j] = bf16(w1[(ks*32 + (lane>>4)*8 + j)*96 + nt*16 + (lane&15)])
__global__ __launch_bounds__(64) void k_w1pack(const float* __restrict__ w1,
                                               unsigned short* __restrict__ w1f) {
    int ks = blockIdx.x / 6, nt = blockIdx.x % 6;
    int l  = threadIdx.x;
    int n  = nt * 16 + (l & 15);
    int k0 = ks * 32 + (l >> 4) * 8;
    unsigned short o[8];
#pragma unroll
    for (int j = 0; j < 8; ++j) o[j] = f2bf(w1[(size_t)(k0 + j) * NI + n]);
    unsigned short* dst = w1f + ((size_t)blockIdx.x * 64 + l) * 8;
#pragma unroll
    for (int j = 0; j < 8; ++j) dst[j] = o[j];
}

// ---------------- Kernel 1: per-token mean / rstd ----------------
// grid: BATCH*16 (64 tokens each), block 256 = 16 token-groups x 16 channel-groups
__global__ __launch_bounds__(256) void k_stats(const float* __restrict__ x,
                                               float2* __restrict__ stats) {
    int bid = blockIdx.x;
    int b   = bid >> 4;
    int p0  = (bid & 15) << 6;
    int lt  = threadIdx.x & 15;   // token group (4 tokens)
    int cg  = threadIdx.x >> 4;   // channel group 0..15
    const float* xb = x + (size_t)b * CH * NP + p0 + lt * 4;
    float4 s = make_float4(0.f,0.f,0.f,0.f);
    float4 q = make_float4(0.f,0.f,0.f,0.f);
#pragma unroll 4
    for (int c = cg; c < CH; c += 16) {
        float4 v = *(const float4*)(xb + (size_t)c * NP);
        s.x += v.x; s.y += v.y; s.z += v.z; s.w += v.w;
        q.x += v.x*v.x; q.y += v.y*v.y; q.z += v.z*v.z; q.w += v.w*v.w;
    }
    __shared__ float4 ls[16][16];
    __shared__ float4 lq[16][16];
    ls[cg][lt] = s; lq[cg][lt] = q;
    __syncthreads();
    for (int st = 8; st > 0; st >>= 1) {
        if (cg < st) {
            float4 s2 = ls[cg + st][lt], q2 = lq[cg + st][lt];
            s.x += s2.x; s.y += s2.y; s.z += s2.z; s.w += s2.w;
            q.x += q2.x; q.y += q2.y; q.z += q2.z; q.w += q2.w;
            ls[cg][lt] = s; lq[cg][lt] = q;
        }
        __syncthreads();
    }
    if (cg == 0) {
        const float inv = 1.0f / (float)CH;
        float2* st = stats + (size_t)b * NP + p0 + lt * 4;
        float mu, var;
        mu = s.x * inv; var = q.x * inv - mu * mu; st[0] = make_float2(mu, rsqrtf(var + EPSF));
        mu = s.y * inv; var = q.y * inv - mu * mu; st[1] = make_float2(mu, rsqrtf(var + EPSF));
        mu = s.z * inv; var = q.z * inv - mu * mu; st[2] = make_float2(mu, rsqrtf(var + EPSF));
        mu = s.w * inv; var = q.w * inv - mu * mu; st[3] = make_float2(mu, rsqrtf(var + EPSF));
    }
}

// ---------------- Kernel 2: LN + MLP via MFMA -> logits ----------------
// grid: BATCH*8 blocks, block 256 = 4 waves; each wave: 32 tokens x N=96 x K=768.
// A-frag (lane&15 = token, k = ks*32 + (lane>>4)*8 + j) built on the fly from x + stats (LN fused).
// B-frag loaded from pre-packed w1f (L2-resident).
__global__ __launch_bounds__(256) void k_mlp(const float* __restrict__ x,
        const float2* __restrict__ stats,
        const float* __restrict__ gamma, const float* __restrict__ beta,
        const unsigned short* __restrict__ w1f,
        const float* __restrict__ b1, const float* __restrict__ w2,
        const float* __restrict__ b2, float* __restrict__ logits)
{
    int bid  = blockIdx.x;
    int b    = bid >> 3;
    int p0   = (bid & 7) << 7;       // 128 tokens per block
    int wv   = threadIdx.x >> 6;
    int lane = threadIdx.x & 63;
    int m    = lane & 15;
    int kg   = lane >> 4;
    int mt   = p0 + wv * 32;         // wave's 32-token tile

    float2 st0 = stats[(size_t)b * NP + mt + m];
    float2 st1 = stats[(size_t)b * NP + mt + 16 + m];
    const float* xb = x + (size_t)b * CH * NP + mt + m;

    f32x4 accA[6], accB[6];
#pragma unroll
    for (int nt = 0; nt < 6; ++nt) {
        accA[nt] = (f32x4){0.f,0.f,0.f,0.f};
        accB[nt] = (f32x4){0.f,0.f,0.f,0.f};
    }
    const short8* wfp = (const short8*)w1f;

    for (int ks = 0; ks < 24; ++ks) {
        int cb = ks * 32 + kg * 8;
        const float* xc = xb + (size_t)cb * NP;
        float xv0[8], xv1[8];
#pragma unroll
        for (int j = 0; j < 8; ++j) {
            xv0[j] = xc[(size_t)j * NP];
            xv1[j] = xc[(size_t)j * NP + 16];
        }
        float4 g0 = *(const float4*)(gamma + cb);
        float4 g1 = *(const float4*)(gamma + cb + 4);
        float4 e0 = *(const float4*)(beta  + cb);
        float4 e1 = *(const float4*)(beta  + cb + 4);
        float gm[8] = {g0.x,g0.y,g0.z,g0.w,g1.x,g1.y,g1.z,g1.w};
        float bt[8] = {e0.x,e0.y,e0.z,e0.w,e1.x,e1.y,e1.z,e1.w};
        short8 a0, a1;
#pragma unroll
        for (int j = 0; j < 8; ++j) {
            float r0 = st0.y * gm[j];
            float r1 = st1.y * gm[j];
            float x0 = fmaf(xv0[j], r0, bt[j] - st0.x * r0);
            float x1 = fmaf(xv1[j], r1, bt[j] - st1.x * r1);
            a0[j] = (short)f2bf(x0);
            a1[j] = (short)f2bf(x1);
        }
        const short8* wk = wfp + (size_t)ks * 6 * 64 + lane;
#pragma unroll
        for (int nt = 0; nt < 6; ++nt) {
            short8 bf = wk[nt * 64];
            accA[nt] = __builtin_amdgcn_mfma_f32_16x16x32_bf16(a0, bf, accA[nt], 0, 0, 0);
            accB[nt] = __builtin_amdgcn_mfma_f32_16x16x32_bf16(a1, bf, accB[nt], 0, 0, 0);
        }
    }

    // epilogue: h = gelu(acc + b1); logits = h @ w2 + b2
    int nlo = lane & 15;
    float4 b2a = *(const float4*)b2;
    float4 b2b = *(const float4*)(b2 + 4);
#pragma unroll
    for (int half = 0; half < 2; ++half) {
        float lg[4][8];
#pragma unroll
        for (int r = 0; r < 4; ++r)
#pragma unroll
            for (int t = 0; t < 8; ++t) lg[r][t] = 0.f;
#pragma unroll
        for (int nt = 0; nt < 6; ++nt) {
            int n = nt * 16 + nlo;
            float b1v = b1[n];
            float4 w2a = *(const float4*)(w2 + n * 8);
            float4 w2b = *(const float4*)(w2 + n * 8 + 4);
            f32x4 ac = half ? accB[nt] : accA[nt];
#pragma unroll
            for (int r = 0; r < 4; ++r) {
                float h = ac[r] + b1v;
                h = 0.5f * h * (1.0f + erff(h * 0.70710678118654752f));
                lg[r][0] += h * w2a.x; lg[r][1] += h * w2a.y;
                lg[r][2] += h * w2a.z; lg[r][3] += h * w2a.w;
                lg[r][4] += h * w2b.x; lg[r][5] += h * w2b.y;
                lg[r][6] += h * w2b.z; lg[r][7] += h * w2b.w;
            }
        }
#pragma unroll
        for (int mask = 1; mask <= 8; mask <<= 1)
#pragma unroll
            for (int r = 0; r < 4; ++r)
#pragma unroll
                for (int t = 0; t < 8; ++t)
                    lg[r][t] += __shfl_xor(lg[r][t], mask, 64);
        if (nlo == 0) {
#pragma unroll
            for (int r = 0; r < 4; ++r) {
                int pp = mt + half * 16 + kg * 4 + r;
                float* op = logits + ((size_t)b * NP + pp) * NT;
                *(float4*)op       = make_float4(lg[r][0] + b2a.x, lg[r][1] + b2a.y,
                                                 lg[r][2] + b2a.z, lg[r][3] + b2a.w);
                *(float4*)(op + 4) = make_float4(lg[r][4] + b2b.x, lg[r][5] + b2b.y,
                                                 lg[r][6] + b2b.z, lg[r][7] + b2b.w);
            }
        }
    }
}

// ---------------- Kernel 3: fused softmax + out ----------------
// grid: BATCH*12 (64 channels each), block 256. Each block redoes the (cheap) softmax for its
// batch from logits, builds g = rstd*attn in registers, then out = (gamma*(x·g - S2) + beta)/1024.
__global__ __launch_bounds__(256) void k_out(const float* __restrict__ x,
        const float* __restrict__ logits, const float2* __restrict__ stats,
        const float* __restrict__ gamma, const float* __restrict__ beta,
        float* __restrict__ out)
{
    int b   = blockIdx.x / 12;
    int c0  = (blockIdx.x % 12) * 64;
    int tid = threadIdx.x;
    int lane = tid & 63, wv = tid >> 6;
    __shared__ float gT[NT][NP];     // 32 KB
    __shared__ float red[4][16];

    const float* lgp = logits + (size_t)b * NP * NT;
    const float2* stb = stats + (size_t)b * NP;
    float e[4][NT];
    float2 st4[4];
#pragma unroll
    for (int k = 0; k < 4; ++k) {
        int p = tid + 256 * k;
        float4 a  = *(const float4*)(lgp + (size_t)p * NT);
        float4 bq = *(const float4*)(lgp + (size_t)p * NT + 4);
        e[k][0]=a.x; e[k][1]=a.y; e[k][2]=a.z; e[k][3]=a.w;
        e[k][4]=bq.x; e[k][5]=bq.y; e[k][6]=bq.z; e[k][7]=bq.w;
        st4[k] = stb[p];
    }
    float mx[NT];
#pragma unroll
    for (int t = 0; t < NT; ++t)
        mx[t] = fmaxf(fmaxf(e[0][t], e[1][t]), fmaxf(e[2][t], e[3][t]));
#pragma unroll
    for (int mask = 1; mask <= 32; mask <<= 1)
#pragma unroll
        for (int t = 0; t < NT; ++t)
            mx[t] = fmaxf(mx[t], __shfl_xor(mx[t], mask, 64));
    if (lane == 0) {
#pragma unroll
        for (int t = 0; t < NT; ++t) red[wv][t] = mx[t];
    }
    __syncthreads();
#pragma unroll
    for (int t = 0; t < NT; ++t)
        mx[t] = fmaxf(fmaxf(red[0][t], red[1][t]), fmaxf(red[2][t], red[3][t]));
    __syncthreads();

    float sm[NT], s2p[NT];
#pragma unroll
    for (int t = 0; t < NT; ++t) { sm[t] = 0.f; s2p[t] = 0.f; }
#pragma unroll
    for (int k = 0; k < 4; ++k) {
        float mr = st4[k].x * st4[k].y;    // mu * rstd
#pragma unroll
        for (int t = 0; t < NT; ++t) {
            e[k][t] = expf(e[k][t] - mx[t]);
            sm[t]  += e[k][t];
            s2p[t] += mr * e[k][t];
        }
    }
#pragma unroll
    for (int mask = 1; mask <= 32; mask <<= 1)
#pragma unroll
        for (int t = 0; t < NT; ++t) {
            sm[t]  += __shfl_xor(sm[t],  mask, 64);
            s2p[t] += __shfl_xor(s2p[t], mask, 64);
        }
    if (lane == 0) {
#pragma unroll
        for (int t = 0; t < NT; ++t) { red[wv][t] = sm[t]; red[wv][8 + t] = s2p[t]; }
    }
    __syncthreads();
    float inv[NT], s2f[NT];
#pragma unroll
    for (int t = 0; t < NT; ++t) {
        float s  = red[0][t] + red[1][t] + red[2][t] + red[3][t];
        float s2 = red[0][8+t] + red[1][8+t] + red[2][8+t] + red[3][8+t];
        inv[t] = 1.0f / s;
        s2f[t] = s2 * inv[t];
    }
#pragma unroll
    for (int k = 0; k < 4; ++k)
#pragma unroll
        for (int t = 0; t < NT; ++t)
            gT[t][tid + 256 * k] = st4[k].y * e[k][t] * inv[t];   // rstd * attn
    __syncthreads();

    // g into registers: lane owns p = lane + 64*k2
    float greg[16][NT];
#pragma unroll
    for (int k2 = 0; k2 < 16; ++k2)
#pragma unroll
        for (int t = 0; t < NT; ++t)
            greg[k2][t] = gT[t][lane + 64 * k2];

    const float sc = 1.0f / (float)NP;
    for (int ch = 0; ch < 16; ++ch) {
        int c = c0 + wv * 16 + ch;
        const float* xr = x + ((size_t)b * CH + c) * NP;
        float xvv[16];
#pragma unroll
        for (int k2 = 0; k2 < 16; ++k2) xvv[k2] = xr[k2 * 64 + lane];
        float a[NT];
#pragma unroll
        for (int t = 0; t < NT; ++t) a[t] = 0.f;
#pragma unroll
        for (int k2 = 0; k2 < 16; ++k2)
#pragma unroll
            for (int t = 0; t < NT; ++t)
                a[t] = fmaf(xvv[k2], greg[k2][t], a[t]);
#pragma unroll
        for (int mask = 1; mask <= 32; mask <<= 1)
#pragma unroll
            for (int t = 0; t < NT; ++t)
                a[t] += __shfl_xor(a[t], mask, 64);
        if (lane == 0) {
            float ga = gamma[c] * sc, be = beta[c] * sc;
            float* op = out + ((size_t)b * CH + c) * NT;
            *(float4*)op       = make_float4(ga*(a[0]-s2f[0])+be, ga*(a[1]-s2f[1])+be,
                                             ga*(a[2]-s2f[2])+be, ga*(a[3]-s2f[3])+be);
            *(float4*)(op + 4) = make_float4(ga*(a[4]-s2f[4])+be, ga*(a[5]-s2f[5])+be,
                                             ga*(a[6]-s2f[6])+be, ga*(a[7]-s2f[7])+be);
        }
    }
}

extern "C" void kernel_launch(void* const* d_in, const int* in_sizes, int n_in,
                              void* d_out, int out_size, void* d_ws, size_t ws_size,
                              hipStream_t stream) {
    const float* x     = (const float*)d_in[0];
    const float* gamma = (const float*)d_in[1];
    const float* beta  = (const float*)d_in[2];
    const float* w1    = (const float*)d_in[3];
    const float* b1    = (const float*)d_in[4];
    const float* w2    = (const float*)d_in[5];
    const float* b2    = (const float*)d_in[6];
    float* out = (float*)d_out;

    char* ws = (char*)d_ws;
    float2*         stats  = (float2*)ws;                                   // 512 KB
    float*          lgbuf  = (float*)(ws + (size_t)BATCH*NP*sizeof(float2));// 2 MB
    unsigned short* w1f    = (unsigned short*)(ws + (size_t)BATCH*NP*sizeof(float2)
                                                  + (size_t)BATCH*NP*NT*sizeof(float)); // 144 KB

    k_w1pack<<<24 * 6,     64,  0, stream>>>(w1, w1f);
    k_stats <<<BATCH * 16, 256, 0, stream>>>(x, stats);
    k_mlp   <<<BATCH * 8,  256, 0, stream>>>(x, stats, gamma, beta, w1f, b1, w2, b2, lgbuf);
    k_out   <<<BATCH * 12, 256, 0, stream>>>(x, lgbuf, stats, gamma, beta, out);
}

// Round 3
// 353.769 us; speedup vs baseline: 2.1736x; 1.0769x over previous
//
#include <hip/hip_runtime.h>
#include <hip/hip_bf16.h>
#include <math.h>

#define BATCH 64
#define CH    768
#define NP    1024
#define NI    96
#define NT    8
#define EPSF  1e-5f

typedef __attribute__((ext_vector_type(8))) short  short8;
typedef __attribute__((ext_vector_type(4))) float  f32x4;

__device__ __forceinline__ short bfs(float f) {
    __hip_bfloat16 h = __float2bfloat16(f);   // RTNE; compiler fuses pairs into v_cvt_pk_bf16_f32
    return *reinterpret_cast<short*>(&h);
}

// ---------------- Kernel 0: pack w1 (fp32 [768][96]) -> bf16 B-fragment layout ----------------
// w1f[((ks*6 + nt)*64 + lane)*8 + j] = bf16(w1[(ks*32 + (lane>>4)*8 + j)*96 + nt*16 + (lane&15)])
__global__ __launch_bounds__(64) void k_w1pack(const float* __restrict__ w1,
                                               unsigned short* __restrict__ w1f) {
    int ks = blockIdx.x / 6, nt = blockIdx.x % 6;
    int l  = threadIdx.x;
    int n  = nt * 16 + (l & 15);
    int k0 = ks * 32 + (l >> 4) * 8;
    short8 o;
#pragma unroll
    for (int j = 0; j < 8; ++j) o[j] = bfs(w1[(size_t)(k0 + j) * NI + n]);
    *(short8*)(w1f + ((size_t)blockIdx.x * 64 + l) * 8) = o;
}

// ---------------- Kernel 1: fused stats + LN + MLP (MFMA) -> logits, stats ----------------
// grid BATCH*8, block 256 (4 waves x 32-token tiles). Phase 1: coalesced sum/sumsq over the
// block's 128 tokens -> LDS + global stats. Phase 2: A-frags built on the fly (LLC-warm re-read).
__global__ __launch_bounds__(256) void k_mlpf(const float* __restrict__ x,
        const float* __restrict__ gamma, const float* __restrict__ beta,
        const unsigned short* __restrict__ w1f,
        const float* __restrict__ b1, const float* __restrict__ w2,
        const float* __restrict__ b2,
        float2* __restrict__ stats, float* __restrict__ logits)
{
    int bid = blockIdx.x;
    int b   = bid >> 3;
    int p0  = (bid & 7) << 7;        // 128 tokens
    int tid = threadIdx.x;

    __shared__ float4 ls[8][32];
    __shared__ float4 lq[8][32];
    __shared__ float2 stl[128];

    // ---- phase 1: per-token mean / rstd over the 128 tokens ----
    {
        int tg = tid & 31;           // token quad (4 tokens)
        int cg = tid >> 5;           // channel group 0..7
        const float* xb = x + (size_t)b * CH * NP + p0 + tg * 4;
        float4 s = make_float4(0.f,0.f,0.f,0.f);
        float4 q = make_float4(0.f,0.f,0.f,0.f);
#pragma unroll 4
        for (int c = cg; c < CH; c += 8) {
            float4 v = *(const float4*)(xb + (size_t)c * NP);
            s.x += v.x; s.y += v.y; s.z += v.z; s.w += v.w;
            q.x += v.x*v.x; q.y += v.y*v.y; q.z += v.z*v.z; q.w += v.w*v.w;
        }
        ls[cg][tg] = s; lq[cg][tg] = q;
        __syncthreads();
        if (cg == 0) {
#pragma unroll
            for (int k = 1; k < 8; ++k) {
                float4 s2 = ls[k][tg], q2 = lq[k][tg];
                s.x += s2.x; s.y += s2.y; s.z += s2.z; s.w += s2.w;
                q.x += q2.x; q.y += q2.y; q.z += q2.z; q.w += q2.w;
            }
            const float inv = 1.0f / (float)CH;
            float2 r0, r1, r2, r3;
            float mu, var;
            mu = s.x*inv; var = q.x*inv - mu*mu; r0 = make_float2(mu, rsqrtf(var + EPSF));
            mu = s.y*inv; var = q.y*inv - mu*mu; r1 = make_float2(mu, rsqrtf(var + EPSF));
            mu = s.z*inv; var = q.z*inv - mu*mu; r2 = make_float2(mu, rsqrtf(var + EPSF));
            mu = s.w*inv; var = q.w*inv - mu*mu; r3 = make_float2(mu, rsqrtf(var + EPSF));
            stl[tg*4+0] = r0; stl[tg*4+1] = r1; stl[tg*4+2] = r2; stl[tg*4+3] = r3;
            float2* st = stats + (size_t)b * NP + p0 + tg * 4;
            st[0] = r0; st[1] = r1; st[2] = r2; st[3] = r3;
        }
        __syncthreads();
    }

    // ---- phase 2: LN + x@w1 via MFMA ----
    int wv   = tid >> 6;
    int lane = tid & 63;
    int m    = lane & 15;
    int kg   = lane >> 4;
    int mt   = p0 + wv * 32;

    float2 st0 = stl[wv * 32 + m];
    float2 st1 = stl[wv * 32 + 16 + m];
    const float* xb = x + (size_t)b * CH * NP + mt + m;

    f32x4 accA[6], accB[6];
#pragma unroll
    for (int nt = 0; nt < 6; ++nt) {
        accA[nt] = (f32x4){0.f,0.f,0.f,0.f};
        accB[nt] = (f32x4){0.f,0.f,0.f,0.f};
    }
    const short8* wfp = (const short8*)w1f;

    for (int ks = 0; ks < 24; ++ks) {
        int cb = ks * 32 + kg * 8;
        const float* xc = xb + (size_t)cb * NP;
        float xv0[8], xv1[8];
#pragma unroll
        for (int j = 0; j < 8; ++j) {
            xv0[j] = xc[(size_t)j * NP];
            xv1[j] = xc[(size_t)j * NP + 16];
        }
        float4 g0 = *(const float4*)(gamma + cb);
        float4 g1 = *(const float4*)(gamma + cb + 4);
        float4 e0 = *(const float4*)(beta  + cb);
        float4 e1 = *(const float4*)(beta  + cb + 4);
        float gm[8] = {g0.x,g0.y,g0.z,g0.w,g1.x,g1.y,g1.z,g1.w};
        float bt[8] = {e0.x,e0.y,e0.z,e0.w,e1.x,e1.y,e1.z,e1.w};
        short8 a0, a1;
#pragma unroll
        for (int j = 0; j < 8; ++j) {
            float rg0 = st0.y * gm[j];
            float rg1 = st1.y * gm[j];
            a0[j] = bfs(fmaf(xv0[j], rg0, fmaf(-st0.x, rg0, bt[j])));
            a1[j] = bfs(fmaf(xv1[j], rg1, fmaf(-st1.x, rg1, bt[j])));
        }
        const short8* wk = wfp + (size_t)ks * 6 * 64 + lane;
#pragma unroll
        for (int nt = 0; nt < 6; ++nt) {
            short8 bf = wk[nt * 64];
            accA[nt] = __builtin_amdgcn_mfma_f32_16x16x32_bf16(a0, bf, accA[nt], 0, 0, 0);
            accB[nt] = __builtin_amdgcn_mfma_f32_16x16x32_bf16(a1, bf, accB[nt], 0, 0, 0);
        }
    }

    // epilogue: h = gelu(acc + b1); logits = h @ w2 + b2
    int nlo = lane & 15;
    float4 b2a = *(const float4*)b2;
    float4 b2b = *(const float4*)(b2 + 4);
#pragma unroll
    for (int half = 0; half < 2; ++half) {
        float lg[4][8];
#pragma unroll
        for (int r = 0; r < 4; ++r)
#pragma unroll
            for (int t = 0; t < 8; ++t) lg[r][t] = 0.f;
#pragma unroll
        for (int nt = 0; nt < 6; ++nt) {
            int n = nt * 16 + nlo;
            float b1v = b1[n];
            float4 w2a = *(const float4*)(w2 + n * 8);
            float4 w2b = *(const float4*)(w2 + n * 8 + 4);
            f32x4 ac = half ? accB[nt] : accA[nt];
#pragma unroll
            for (int r = 0; r < 4; ++r) {
                float h = ac[r] + b1v;
                h = 0.5f * h * (1.0f + erff(h * 0.70710678118654752f));
                lg[r][0] += h * w2a.x; lg[r][1] += h * w2a.y;
                lg[r][2] += h * w2a.z; lg[r][3] += h * w2a.w;
                lg[r][4] += h * w2b.x; lg[r][5] += h * w2b.y;
                lg[r][6] += h * w2b.z; lg[r][7] += h * w2b.w;
            }
        }
#pragma unroll
        for (int mask = 1; mask <= 8; mask <<= 1)
#pragma unroll
            for (int r = 0; r < 4; ++r)
#pragma unroll
                for (int t = 0; t < 8; ++t)
                    lg[r][t] += __shfl_xor(lg[r][t], mask, 64);
        if (nlo == 0) {
#pragma unroll
            for (int r = 0; r < 4; ++r) {
                int pp = mt + half * 16 + kg * 4 + r;
                float* op = logits + ((size_t)b * NP + pp) * NT;
                *(float4*)op       = make_float4(lg[r][0] + b2a.x, lg[r][1] + b2a.y,
                                                 lg[r][2] + b2a.z, lg[r][3] + b2a.w);
                *(float4*)(op + 4) = make_float4(lg[r][4] + b2b.x, lg[r][5] + b2b.y,
                                                 lg[r][6] + b2b.z, lg[r][7] + b2b.w);
            }
        }
    }
}

// ---------------- Kernel 2: softmax over tokens -> g (bf16 B-frag layout) + S2 ----------------
// grid BATCH, block 256. gbf[b][ks*64+lane][j] = bf16(g[ks*32+(lane>>4)*8+j][lane&15]), 0 if n>=8.
__global__ __launch_bounds__(256) void k_g(const float* __restrict__ logits,
        const float2* __restrict__ stats,
        unsigned short* __restrict__ gbf, float* __restrict__ S2)
{
    int b = blockIdx.x;
    int tid = threadIdx.x;
    int lane = tid & 63, wv = tid >> 6;
    __shared__ float gs[NP][NT];     // 32 KB
    __shared__ float red[4][16];

    const float* lgp = logits + (size_t)b * NP * NT;
    const float2* stb = stats + (size_t)b * NP;
    float e[4][NT];
    float2 st4[4];
#pragma unroll
    for (int k = 0; k < 4; ++k) {
        int p = tid + 256 * k;
        float4 a  = *(const float4*)(lgp + (size_t)p * NT);
        float4 bq = *(const float4*)(lgp + (size_t)p * NT + 4);
        e[k][0]=a.x; e[k][1]=a.y; e[k][2]=a.z; e[k][3]=a.w;
        e[k][4]=bq.x; e[k][5]=bq.y; e[k][6]=bq.z; e[k][7]=bq.w;
        st4[k] = stb[p];
    }
    float mx[NT];
#pragma unroll
    for (int t = 0; t < NT; ++t)
        mx[t] = fmaxf(fmaxf(e[0][t], e[1][t]), fmaxf(e[2][t], e[3][t]));
#pragma unroll
    for (int mask = 1; mask <= 32; mask <<= 1)
#pragma unroll
        for (int t = 0; t < NT; ++t)
            mx[t] = fmaxf(mx[t], __shfl_xor(mx[t], mask, 64));
    if (lane == 0) {
#pragma unroll
        for (int t = 0; t < NT; ++t) red[wv][t] = mx[t];
    }
    __syncthreads();
#pragma unroll
    for (int t = 0; t < NT; ++t)
        mx[t] = fmaxf(fmaxf(red[0][t], red[1][t]), fmaxf(red[2][t], red[3][t]));
    __syncthreads();

    float sm[NT], s2p[NT];
#pragma unroll
    for (int t = 0; t < NT; ++t) { sm[t] = 0.f; s2p[t] = 0.f; }
#pragma unroll
    for (int k = 0; k < 4; ++k) {
        float mr = st4[k].x * st4[k].y;   // mu * rstd
#pragma unroll
        for (int t = 0; t < NT; ++t) {
            e[k][t] = expf(e[k][t] - mx[t]);
            sm[t]  += e[k][t];
            s2p[t] += mr * e[k][t];
        }
    }
#pragma unroll
    for (int mask = 1; mask <= 32; mask <<= 1)
#pragma unroll
        for (int t = 0; t < NT; ++t) {
            sm[t]  += __shfl_xor(sm[t],  mask, 64);
            s2p[t] += __shfl_xor(s2p[t], mask, 64);
        }
    if (lane == 0) {
#pragma unroll
        for (int t = 0; t < NT; ++t) { red[wv][t] = sm[t]; red[wv][8 + t] = s2p[t]; }
    }
    __syncthreads();
    float inv[NT], s2f[NT];
#pragma unroll
    for (int t = 0; t < NT; ++t) {
        float s  = red[0][t] + red[1][t] + red[2][t] + red[3][t];
        float s2 = red[0][8+t] + red[1][8+t] + red[2][8+t] + red[3][8+t];
        inv[t] = 1.0f / s;
        s2f[t] = s2 * inv[t];
    }
    if (tid < NT) S2[b * NT + tid] = s2f[tid];

#pragma unroll
    for (int k = 0; k < 4; ++k)
#pragma unroll
        for (int t = 0; t < NT; ++t)
            gs[tid + 256 * k][t] = st4[k].y * e[k][t] * inv[t];   // rstd * attn
    __syncthreads();

    // pack 2048 B-frag slots (32 ks x 64 lanes), 8 per thread
    unsigned short* gb = gbf + (size_t)b * 2048 * 8;
#pragma unroll
    for (int ss = 0; ss < 8; ++ss) {
        int slot   = tid * 8 + ss;
        int lane_s = slot & 63;
        int ks     = slot >> 6;
        int n      = lane_s & 15;
        int k0     = ks * 32 + (lane_s >> 4) * 8;
        short8 o = (short8){0,0,0,0,0,0,0,0};
        if (n < 8) {
#pragma unroll
            for (int j = 0; j < 8; ++j) o[j] = bfs(gs[k0 + j][n]);
        }
        *(short8*)(gb + (size_t)slot * 8) = o;
    }
}

// ---------------- Kernel 3: out[b,c,n] = (gamma_c*(x[b,c,:]·g[:,n] - S2[n]) + beta_c)/1024 ----------------
// MFMA GEMM: M=16 channels/wave, N=16 (8 used), K=1024. grid BATCH*12, block 256 (4 waves).
__global__ __launch_bounds__(256) void k_outg(const float* __restrict__ x,
        const unsigned short* __restrict__ gbf, const float* __restrict__ S2,
        const float* __restrict__ gamma, const float* __restrict__ beta,
        float* __restrict__ out)
{
    int b   = blockIdx.x / 12;
    int c0  = (blockIdx.x % 12) * 64;
    int tid = threadIdx.x, lane = tid & 63, wv = tid >> 6;
    int kg  = lane >> 4, m = lane & 15, n = lane & 15;
    int cw  = c0 + wv * 16;

    const float*  xr = x + ((size_t)b * CH + cw + m) * NP + kg * 8;
    const short8* gb = (const short8*)gbf + (size_t)b * 2048;

    f32x4 acc0 = (f32x4){0.f,0.f,0.f,0.f};
    f32x4 acc1 = (f32x4){0.f,0.f,0.f,0.f};
#pragma unroll 4
    for (int ks = 0; ks < 32; ks += 2) {
        float4 v0 = *(const float4*)(xr + ks * 32);
        float4 v1 = *(const float4*)(xr + ks * 32 + 4);
        float4 v2 = *(const float4*)(xr + ks * 32 + 32);
        float4 v3 = *(const float4*)(xr + ks * 32 + 36);
        short8 a0, a1;
        a0[0]=bfs(v0.x); a0[1]=bfs(v0.y); a0[2]=bfs(v0.z); a0[3]=bfs(v0.w);
        a0[4]=bfs(v1.x); a0[5]=bfs(v1.y); a0[6]=bfs(v1.z); a0[7]=bfs(v1.w);
        a1[0]=bfs(v2.x); a1[1]=bfs(v2.y); a1[2]=bfs(v2.z); a1[3]=bfs(v2.w);
        a1[4]=bfs(v3.x); a1[5]=bfs(v3.y); a1[6]=bfs(v3.z); a1[7]=bfs(v3.w);
        short8 bf0 = gb[ks * 64 + lane];
        short8 bf1 = gb[(ks + 1) * 64 + lane];
        acc0 = __builtin_amdgcn_mfma_f32_16x16x32_bf16(a0, bf0, acc0, 0, 0, 0);
        acc1 = __builtin_amdgcn_mfma_f32_16x16x32_bf16(a1, bf1, acc1, 0, 0, 0);
    }

    if (n < NT) {
        float s2v = S2[b * NT + n];
        const float sc = 1.0f / (float)NP;
#pragma unroll
        for (int r = 0; r < 4; ++r) {
            int c = cw + kg * 4 + r;
            float val = acc0[r] + acc1[r];
            out[((size_t)b * CH + c) * NT + n] = (gamma[c] * (val - s2v) + beta[c]) * sc;
        }
    }
}

extern "C" void kernel_launch(void* const* d_in, const int* in_sizes, int n_in,
                              void* d_out, int out_size, void* d_ws, size_t ws_size,
                              hipStream_t stream) {
    const float* x     = (const float*)d_in[0];
    const float* gamma = (const float*)d_in[1];
    const float* beta  = (const float*)d_in[2];
    const float* w1    = (const float*)d_in[3];
    const float* b1    = (const float*)d_in[4];
    const float* w2    = (const float*)d_in[5];
    const float* b2    = (const float*)d_in[6];
    float* out = (float*)d_out;

    char* ws = (char*)d_ws;
    float2*         stats = (float2*)(ws + 0);                // 512 KiB
    float*          lgbuf = (float*)(ws + 524288);            // 2 MiB
    unsigned short* w1f   = (unsigned short*)(ws + 2621440);  // 144 KiB
    unsigned short* gbf   = (unsigned short*)(ws + 2768896);  // 2 MiB
    float*          S2    = (float*)(ws + 4866048);           // 2 KiB

    k_w1pack<<<24 * 6,     64,  0, stream>>>(w1, w1f);
    k_mlpf  <<<BATCH * 8,  256, 0, stream>>>(x, gamma, beta, w1f, b1, w2, b2, stats, lgbuf);
    k_g     <<<BATCH,      256, 0, stream>>>(lgbuf, stats, gbf, S2);
    k_outg  <<<BATCH * 12, 256, 0, stream>>>(x, gbf, S2, gamma, beta, out);
}